// Round 1
// baseline (3084.917 us; speedup 1.0000x reference)
//
#include <hip/hip_runtime.h>
#include <hip/hip_bf16.h>
#include <math.h>

#define B_DIM 2048
#define L_DIM 2048
#define C_DIM 16
#define F_DIM 1024
#define H_DIM 4096
#define P_DIM 88

// ---------------------------------------------------------------------------
// start_fc: v[b,l] = dot(x[b,l,:16], w_start) + b_start   (memory-bound)
// ---------------------------------------------------------------------------
__global__ __launch_bounds__(256) void start_fc_kernel(
    const float* __restrict__ x, const float* __restrict__ w_start,
    const float* __restrict__ b_start, float* __restrict__ v)
{
    size_t gid = (size_t)blockIdx.x * 256 + threadIdx.x;
    const float4* xp = (const float4*)(x + gid * 16);
    const float4* wp = (const float4*)w_start;
    float acc = b_start[0];
#pragma unroll
    for (int q = 0; q < 4; q++) {
        float4 xv = xp[q];
        float4 wv = wp[q];
        acc += xv.x * wv.x + xv.y * wv.y + xv.z * wv.z + xv.w * wv.w;
    }
    v[gid] = acc;
}

// ---------------------------------------------------------------------------
// 2048-point complex FFT (imag=0 input) per batch row, in LDS.
// Outputs bins 1..1024 (DC dropped), scaled by 1/sqrt(2048)  (norm="ortho").
// ---------------------------------------------------------------------------
__global__ __launch_bounds__(256) void fft_kernel(
    const float* __restrict__ v, float* __restrict__ xr, float* __restrict__ xi)
{
    __shared__ float re[2048];
    __shared__ float im[2048];
    int b = blockIdx.x;
    const float* row = v + (size_t)b * 2048;

    // load in bit-reversed order (11-bit reversal)
    for (int i = threadIdx.x; i < 2048; i += 256) {
        unsigned j = __brev((unsigned)i) >> 21;
        re[i] = row[j];
        im[i] = 0.f;
    }
    __syncthreads();

    for (int s = 1; s <= 11; s++) {
        int half = 1 << (s - 1);
        for (int t = threadIdx.x; t < 1024; t += 256) {
            int j = t & (half - 1);
            int base = (t >> (s - 1)) << s;
            float ang = -6.283185307179586f * (float)j / (float)(1 << s);
            float wr, wi;
            sincosf(ang, &wi, &wr);   // wi = sin, wr = cos
            int i0 = base + j, i1 = i0 + half;
            float br = re[i1], bi = im[i1];
            float tr = br * wr - bi * wi;
            float ti = br * wi + bi * wr;
            float ar = re[i0], ai = im[i0];
            re[i0] = ar + tr; im[i0] = ai + ti;
            re[i1] = ar - tr; im[i1] = ai - ti;
        }
        __syncthreads();
    }

    const float sc = 0.022097086912079612f;  // 1/sqrt(2048)
    for (int t = threadIdx.x; t < 1024; t += 256) {
        xr[(size_t)b * 1024 + t] = re[t + 1] * sc;
        xi[(size_t)b * 1024 + t] = im[t + 1] * sc;
    }
}

// ---------------------------------------------------------------------------
// Complex GEMM (fp32, VALU): [M,K]x[K,N], 64x64 block tile, 16 K-tile,
// 256 threads, 4x4 per-thread micro-tile.
// EPI=0: layer1 -> Or/Oi = relu(acc + bias)   (two outputs)
// EPI=1: layer2 -> Or = sqrt((accR+biasR)^2 + (accI+biasI)^2)  (amp)
// ---------------------------------------------------------------------------
template <int EPI>
__global__ __launch_bounds__(256) void cgemm_kernel(
    const float* __restrict__ Ar, const float* __restrict__ Ai,
    const float* __restrict__ Br, const float* __restrict__ Bi,
    const float* __restrict__ biasR, const float* __restrict__ biasI,
    float* __restrict__ Or, float* __restrict__ Oi,
    int M, int N, int K)
{
    __shared__ float sAr[64][17];
    __shared__ float sAi[64][17];
    __shared__ float sBr[16][64];
    __shared__ float sBi[16][64];

    int tid = threadIdx.x;
    int n0 = blockIdx.x * 64;
    int m0 = blockIdx.y * 64;

    int la_m = tid >> 2;            // 0..63
    int la_k = (tid & 3) * 4;       // 0,4,8,12
    int lb_k = tid >> 4;            // 0..15
    int lb_n = (tid & 15) * 4;      // 0..60
    int tm = (tid >> 4) * 4;        // 0..60
    int tn = (tid & 15) * 4;        // 0..60

    float accR[4][4] = {};
    float accI[4][4] = {};

    for (int k0 = 0; k0 < K; k0 += 16) {
        float4 a4r = *(const float4*)&Ar[(size_t)(m0 + la_m) * K + k0 + la_k];
        float4 a4i = *(const float4*)&Ai[(size_t)(m0 + la_m) * K + k0 + la_k];
        float4 b4r = *(const float4*)&Br[(size_t)(k0 + lb_k) * N + n0 + lb_n];
        float4 b4i = *(const float4*)&Bi[(size_t)(k0 + lb_k) * N + n0 + lb_n];

        __syncthreads();   // previous iteration's compute done before overwrite
        sAr[la_m][la_k + 0] = a4r.x; sAr[la_m][la_k + 1] = a4r.y;
        sAr[la_m][la_k + 2] = a4r.z; sAr[la_m][la_k + 3] = a4r.w;
        sAi[la_m][la_k + 0] = a4i.x; sAi[la_m][la_k + 1] = a4i.y;
        sAi[la_m][la_k + 2] = a4i.z; sAi[la_m][la_k + 3] = a4i.w;
        *(float4*)&sBr[lb_k][lb_n] = b4r;
        *(float4*)&sBi[lb_k][lb_n] = b4i;
        __syncthreads();

#pragma unroll
        for (int kk = 0; kk < 16; kk++) {
            float ar[4], ai[4];
#pragma unroll
            for (int i = 0; i < 4; i++) {
                ar[i] = sAr[tm + i][kk];
                ai[i] = sAi[tm + i][kk];
            }
            float4 brv = *(const float4*)&sBr[kk][tn];
            float4 biv = *(const float4*)&sBi[kk][tn];
            float br[4] = {brv.x, brv.y, brv.z, brv.w};
            float bi[4] = {biv.x, biv.y, biv.z, biv.w};
#pragma unroll
            for (int i = 0; i < 4; i++) {
#pragma unroll
                for (int j = 0; j < 4; j++) {
                    accR[i][j] += ar[i] * br[j] - ai[i] * bi[j];
                    accI[i][j] += ai[i] * br[j] + ar[i] * bi[j];
                }
            }
        }
    }

    float4 bR = *(const float4*)&biasR[n0 + tn];
    float4 bI = *(const float4*)&biasI[n0 + tn];
    float brr[4] = {bR.x, bR.y, bR.z, bR.w};
    float bii[4] = {bI.x, bI.y, bI.z, bI.w};

#pragma unroll
    for (int i = 0; i < 4; i++) {
        size_t m = (size_t)(m0 + tm + i);
        if (EPI == 0) {
            float4 vr, vi;
            float r0 = accR[i][0] + brr[0], r1 = accR[i][1] + brr[1];
            float r2 = accR[i][2] + brr[2], r3 = accR[i][3] + brr[3];
            float q0 = accI[i][0] + bii[0], q1 = accI[i][1] + bii[1];
            float q2 = accI[i][2] + bii[2], q3 = accI[i][3] + bii[3];
            vr.x = fmaxf(r0, 0.f); vr.y = fmaxf(r1, 0.f);
            vr.z = fmaxf(r2, 0.f); vr.w = fmaxf(r3, 0.f);
            vi.x = fmaxf(q0, 0.f); vi.y = fmaxf(q1, 0.f);
            vi.z = fmaxf(q2, 0.f); vi.w = fmaxf(q3, 0.f);
            *(float4*)&Or[m * N + n0 + tn] = vr;
            *(float4*)&Oi[m * N + n0 + tn] = vi;
        } else {
            float4 va;
#pragma unroll
            for (int j = 0; j < 4; j++) {
                float r = accR[i][j] + brr[j];
                float q = accI[i][j] + bii[j];
                ((float*)&va)[j] = sqrtf(r * r + q * q);
            }
            *(float4*)&Or[m * N + n0 + tn] = va;
        }
    }
}

// ---------------------------------------------------------------------------
// Router: logits = amp@w_gate + noise_z * (softplus(amp@w_noise)+eps);
// top-3 (ties -> lowest index), softmax over top-3, scatter into gates.
// One block per batch row.
// ---------------------------------------------------------------------------
__global__ __launch_bounds__(128) void router_kernel(
    const float* __restrict__ amp, const float* __restrict__ w_gate,
    const float* __restrict__ w_noise, const float* __restrict__ noise_z,
    float* __restrict__ gates)
{
    __shared__ float s_amp[1024];
    __shared__ float s_logit[P_DIM];
    __shared__ int   s_idx[3];
    __shared__ float s_val[3];

    int b = blockIdx.x;
    for (int i = threadIdx.x; i < 1024; i += 128)
        s_amp[i] = amp[(size_t)b * 1024 + i];
    __syncthreads();

    int p = threadIdx.x;
    if (p < P_DIM) {
        float cg = 0.f, cn = 0.f;
        for (int k = 0; k < 1024; k++) {
            float a = s_amp[k];
            cg = fmaf(a, w_gate[k * P_DIM + p], cg);
            cn = fmaf(a, w_noise[k * P_DIM + p], cn);
        }
        float ns = (cn > 20.f) ? cn : log1pf(expf(cn));   // softplus
        ns += 0.01f;
        s_logit[p] = cg + noise_z[(size_t)b * P_DIM + p] * ns;
    }
    __syncthreads();

    if (threadIdx.x == 0) {
        int i0 = -1, i1 = -1, i2 = -1;
        float v0 = -1e30f, v1 = -1e30f, v2 = -1e30f;
        for (int i = 0; i < P_DIM; i++) {
            float t = s_logit[i];
            if (t > v0) { v0 = t; i0 = i; }
        }
        for (int i = 0; i < P_DIM; i++) {
            if (i == i0) continue;
            float t = s_logit[i];
            if (t > v1) { v1 = t; i1 = i; }
        }
        for (int i = 0; i < P_DIM; i++) {
            if (i == i0 || i == i1) continue;
            float t = s_logit[i];
            if (t > v2) { v2 = t; i2 = i; }
        }
        s_idx[0] = i0; s_idx[1] = i1; s_idx[2] = i2;
        s_val[0] = v0; s_val[1] = v1; s_val[2] = v2;
    }
    __syncthreads();

    if (p < P_DIM) {
        float m = s_val[0];  // already the max
        float e0 = expf(s_val[0] - m);
        float e1 = expf(s_val[1] - m);
        float e2 = expf(s_val[2] - m);
        float inv = 1.f / (e0 + e1 + e2);
        float g = 0.f;
        if (p == s_idx[0]) g = e0 * inv;
        else if (p == s_idx[1]) g = e1 * inv;
        else if (p == s_idx[2]) g = e2 * inv;
        gates[(size_t)b * P_DIM + p] = g;
    }
}

// ---------------------------------------------------------------------------
extern "C" void kernel_launch(void* const* d_in, const int* in_sizes, int n_in,
                              void* d_out, int out_size, void* d_ws, size_t ws_size,
                              hipStream_t stream)
{
    const float* x       = (const float*)d_in[0];
    const float* w_start = (const float*)d_in[1];
    const float* b_start = (const float*)d_in[2];
    const float* w1      = (const float*)d_in[3];  // [2, F, H]
    const float* b1      = (const float*)d_in[4];  // [2, H]
    const float* w2      = (const float*)d_in[5];  // [2, H, F]
    const float* b2      = (const float*)d_in[6];  // [2, F]
    const float* w_gate  = (const float*)d_in[7];  // [F, P]
    const float* w_noise = (const float*)d_in[8];  // [F, P]
    const float* noise_z = (const float*)d_in[9];  // [B, P]
    float* gates = (float*)d_out;

    float* ws  = (float*)d_ws;
    float* v   = ws;                                   // [B, L]      16 MB
    float* xr  = v  + (size_t)B_DIM * L_DIM;           // [B, F]       8 MB
    float* xi  = xr + (size_t)B_DIM * F_DIM;           // [B, F]       8 MB
    float* o1r = xi + (size_t)B_DIM * F_DIM;           // [B, H]      32 MB
    float* o1i = o1r + (size_t)B_DIM * H_DIM;          // [B, H]      32 MB
    float* amp = o1i + (size_t)B_DIM * H_DIM;          // [B, F]       8 MB

    start_fc_kernel<<<(B_DIM * L_DIM) / 256, 256, 0, stream>>>(x, w_start, b_start, v);
    fft_kernel<<<B_DIM, 256, 0, stream>>>(v, xr, xi);
    cgemm_kernel<0><<<dim3(H_DIM / 64, B_DIM / 64), 256, 0, stream>>>(
        xr, xi, w1, w1 + (size_t)F_DIM * H_DIM, b1, b1 + H_DIM,
        o1r, o1i, B_DIM, H_DIM, F_DIM);
    cgemm_kernel<1><<<dim3(F_DIM / 64, B_DIM / 64), 256, 0, stream>>>(
        o1r, o1i, w2, w2 + (size_t)H_DIM * F_DIM, b2, b2 + F_DIM,
        amp, nullptr, B_DIM, F_DIM, H_DIM);
    router_kernel<<<B_DIM, 128, 0, stream>>>(amp, w_gate, w_noise, noise_z, gates);
}

// Round 2
// 758.625 us; speedup vs baseline: 4.0665x; 4.0665x over previous
//
#include <hip/hip_runtime.h>
#include <hip/hip_bf16.h>
#include <math.h>

#define B_DIM 2048
#define L_DIM 2048
#define F_DIM 1024
#define H_DIM 4096
#define P_DIM 88

typedef unsigned short u16;
typedef short bf16x8 __attribute__((ext_vector_type(8)));
typedef float f32x4 __attribute__((ext_vector_type(4)));

// ---- bf16 split helpers (RNE) ----
__device__ __forceinline__ u16 f2bf(float x) {
    unsigned u = __float_as_uint(x);
    return (u16)((u + 0x7fffu + ((u >> 16) & 1u)) >> 16);
}
__device__ __forceinline__ float bf2f(u16 h) {
    return __uint_as_float(((unsigned)h) << 16);
}

// ---- async global->LDS, 16B per lane (CK-style addrspace plumbing) ----
__device__ __forceinline__ void gload_lds16(const void* g, void* l) {
    unsigned loff = (unsigned)(uintptr_t)l;  // LDS offset lives in low 32 bits
    __builtin_amdgcn_global_load_lds(
        reinterpret_cast<const __attribute__((address_space(1))) void*>(
            reinterpret_cast<uintptr_t>(g)),
        reinterpret_cast<__attribute__((address_space(3))) void*>(loff),
        16, 0, 0);
}

// ---------------------------------------------------------------------------
// start_fc: v[b,l] = dot(x[b,l,:16], w_start) + b_start
// ---------------------------------------------------------------------------
__global__ __launch_bounds__(256) void start_fc_kernel(
    const float* __restrict__ x, const float* __restrict__ w_start,
    const float* __restrict__ b_start, float* __restrict__ v)
{
    size_t gid = (size_t)blockIdx.x * 256 + threadIdx.x;
    const float4* xp = (const float4*)(x + gid * 16);
    const float4* wp = (const float4*)w_start;
    float acc = b_start[0];
#pragma unroll
    for (int q = 0; q < 4; q++) {
        float4 xv = xp[q];
        float4 wv = wp[q];
        acc += xv.x * wv.x + xv.y * wv.y + xv.z * wv.z + xv.w * wv.w;
    }
    v[gid] = acc;
}

// ---------------------------------------------------------------------------
// 2048-pt FFT per row; writes A1 phys segments [xr_h | xr_l | xi_h | xi_l]
// (bins 1..1024, ortho scale).  A1 row stride = 4096.
// ---------------------------------------------------------------------------
__global__ __launch_bounds__(256) void fft_kernel(
    const float* __restrict__ v, u16* __restrict__ A1)
{
    __shared__ float re[2048];
    __shared__ float im[2048];
    int b = blockIdx.x;
    const float* row = v + (size_t)b * 2048;

    for (int i = threadIdx.x; i < 2048; i += 256) {
        unsigned j = __brev((unsigned)i) >> 21;
        re[i] = row[j];
        im[i] = 0.f;
    }
    __syncthreads();

    for (int s = 1; s <= 11; s++) {
        int half = 1 << (s - 1);
        for (int t = threadIdx.x; t < 1024; t += 256) {
            int j = t & (half - 1);
            int base = (t >> (s - 1)) << s;
            float ang = -6.283185307179586f * (float)j / (float)(1 << s);
            float wr, wi;
            sincosf(ang, &wi, &wr);
            int i0 = base + j, i1 = i0 + half;
            float br = re[i1], bi = im[i1];
            float tr = br * wr - bi * wi;
            float ti = br * wi + bi * wr;
            float ar = re[i0], ai = im[i0];
            re[i0] = ar + tr; im[i0] = ai + ti;
            re[i1] = ar - tr; im[i1] = ai - ti;
        }
        __syncthreads();
    }

    const float sc = 0.022097086912079612f;  // 1/sqrt(2048)
    u16* arow = A1 + (size_t)b * 4096;
    for (int t = threadIdx.x; t < 1024; t += 256) {
        float r = re[t + 1] * sc;
        float q = im[t + 1] * sc;
        u16 rh = f2bf(r); u16 rl = f2bf(r - bf2f(rh));
        u16 ih = f2bf(q); u16 il = f2bf(q - bf2f(ih));
        arow[t] = rh; arow[1024 + t] = rl;
        arow[2048 + t] = ih; arow[3072 + t] = il;
    }
}

// ---------------------------------------------------------------------------
// Weight conversion: w[2][Kc][Nh] fp32 -> BT [2*Nh][4*Kc] bf16 (transposed,
// split).  Row n   (< Nh, "real-out" cols): [h(wr) | l(wr) | h(-wi) | l(-wi)]
// Row Nh+n ("imag-out" cols):               [h(wi) | l(wi) | h(wr)  | l(wr) ]
// ---------------------------------------------------------------------------
__global__ __launch_bounds__(256) void conv_bt_kernel(
    const float* __restrict__ w, u16* __restrict__ BT, int Kc, int Nh)
{
    __shared__ float t0[32][33];
    __shared__ float t1[32][33];
    int k0 = blockIdx.x * 32, n0 = blockIdx.y * 32;
    int tx = threadIdx.x, ty = threadIdx.y;     // (32, 8)
    const float* w0 = w;
    const float* w1 = w + (size_t)Kc * Nh;

#pragma unroll
    for (int i = 0; i < 4; i++) {
        int k = k0 + ty + 8 * i;
        t0[ty + 8 * i][tx] = w0[(size_t)k * Nh + n0 + tx];
        t1[ty + 8 * i][tx] = w1[(size_t)k * Nh + n0 + tx];
    }
    __syncthreads();

    size_t K4 = 4 * (size_t)Kc;
    int k = k0 + tx;
#pragma unroll
    for (int i = 0; i < 4; i++) {
        int nl = ty + 8 * i;
        int n = n0 + nl;
        float br = t0[tx][nl];
        float bi = t1[tx][nl];
        u16 brh = f2bf(br); u16 brl = f2bf(br - bf2f(brh));
        float nbi = -bi;
        u16 nih = f2bf(nbi); u16 nil = f2bf(nbi - bf2f(nih));
        u16 pih = f2bf(bi);  u16 pil = f2bf(bi - bf2f(pih));
        u16* rowr = BT + (size_t)n * K4;
        rowr[0 * Kc + k] = brh; rowr[1 * Kc + k] = brl;
        rowr[2 * Kc + k] = nih; rowr[3 * Kc + k] = nil;
        u16* rowi = BT + (size_t)(Nh + n) * K4;
        rowi[0 * Kc + k] = pih; rowi[1 * Kc + k] = pil;
        rowi[2 * Kc + k] = brh; rowi[3 * Kc + k] = brl;
    }
}

// ---------------------------------------------------------------------------
// Split-bf16 complex GEMM via K-expansion.  Effective K = 6*Kc with segment
// maps  A: [rh, rl, rh, ih, il, ih] -> phys {0,1,0,2,3,2}
//       B: [p0, p0, p1, p2, p2, p3] -> phys {0,0,1,2,2,3}
// m97 structure: 128x128 tile, BK=32, 4 waves, global_load_lds(16B).
// EPI=0: relu(acc+bias) -> split-bf16 into A2 phys layout [M][4*NH]
// EPI=1: raw acc -> fp32 C (bias added later); blockIdx.z = split-K slice
// ---------------------------------------------------------------------------
template <int EPI>
__global__ __launch_bounds__(256, 2) void gemm_split(
    const u16* __restrict__ A, const u16* __restrict__ B,
    const float* __restrict__ biasL, const float* __restrict__ biasR,
    void* __restrict__ OutBase, int Kc, int KcLog, int NH,
    int ksteps_per_z, size_t out_z_stride)
{
    __shared__ u16 lds[8192];          // sA[128][32] | sB[128][32]
    u16* sA = lds;
    u16* sB = lds + 4096;

    const int tid = threadIdx.x;
    const int w = tid >> 6, lane = tid & 63;
    const int wr = w >> 1, wc = w & 1;
    const int n0 = blockIdx.x * 128, m0 = blockIdx.y * 128;
    const int z = blockIdx.z;
    const size_t K4 = 4 * (size_t)Kc;

    // staging: thread covers one 16B chunk per issue; 2 issues each for A,B
    const int rs = lane >> 2;
    const int kloc = (lane & 3) * 8;
    const u16* Ar0 = A + (size_t)(m0 + (w * 2 + 0) * 16 + rs) * K4 + kloc;
    const u16* Ar1 = A + (size_t)(m0 + (w * 2 + 1) * 16 + rs) * K4 + kloc;
    const u16* Br0 = B + (size_t)(n0 + (w * 2 + 0) * 16 + rs) * K4 + kloc;
    const u16* Br1 = B + (size_t)(n0 + (w * 2 + 1) * 16 + rs) * K4 + kloc;
    u16* dA0 = sA + (w * 2 + 0) * 512;   // wave-uniform LDS dests
    u16* dA1 = sA + (w * 2 + 1) * 512;
    u16* dB0 = sB + (w * 2 + 0) * 512;
    u16* dB1 = sB + (w * 2 + 1) * 512;

    const int fr = lane & 15, kb = lane >> 4;
    const u16* fA = sA + ((wr * 64 + fr) * 32 + kb * 8);
    const u16* fB = sB + ((wc * 64 + fr) * 32 + kb * 8);

    f32x4 acc[4][4];
#pragma unroll
    for (int i = 0; i < 4; i++)
#pragma unroll
        for (int j = 0; j < 4; j++)
            acc[i][j] = (f32x4){0.f, 0.f, 0.f, 0.f};

    const int segA[6] = {0, 1, 0, 2, 3, 2};
    const int segB[6] = {0, 0, 1, 2, 2, 3};

    const int it0 = z * ksteps_per_z, it1 = it0 + ksteps_per_z;
    for (int it = it0; it < it1; ++it) {
        int k0 = it << 5;
        int seg = k0 >> KcLog;
        int kk = k0 & (Kc - 1);
        int ac = segA[seg] * Kc + kk;
        int bc = segB[seg] * Kc + kk;
        gload_lds16(Ar0 + ac, dA0);
        gload_lds16(Ar1 + ac, dA1);
        gload_lds16(Br0 + bc, dB0);
        gload_lds16(Br1 + bc, dB1);
        __syncthreads();                 // vmcnt(0) drain + barrier

        bf16x8 a0 = *(const bf16x8*)(fA + 0 * 512);
        bf16x8 a1 = *(const bf16x8*)(fA + 1 * 512);
        bf16x8 a2 = *(const bf16x8*)(fA + 2 * 512);
        bf16x8 a3 = *(const bf16x8*)(fA + 3 * 512);
        bf16x8 b0 = *(const bf16x8*)(fB + 0 * 512);
        bf16x8 b1 = *(const bf16x8*)(fB + 1 * 512);
        bf16x8 b2 = *(const bf16x8*)(fB + 2 * 512);
        bf16x8 b3 = *(const bf16x8*)(fB + 3 * 512);

        acc[0][0] = __builtin_amdgcn_mfma_f32_16x16x32_bf16(a0, b0, acc[0][0], 0, 0, 0);
        acc[0][1] = __builtin_amdgcn_mfma_f32_16x16x32_bf16(a0, b1, acc[0][1], 0, 0, 0);
        acc[0][2] = __builtin_amdgcn_mfma_f32_16x16x32_bf16(a0, b2, acc[0][2], 0, 0, 0);
        acc[0][3] = __builtin_amdgcn_mfma_f32_16x16x32_bf16(a0, b3, acc[0][3], 0, 0, 0);
        acc[1][0] = __builtin_amdgcn_mfma_f32_16x16x32_bf16(a1, b0, acc[1][0], 0, 0, 0);
        acc[1][1] = __builtin_amdgcn_mfma_f32_16x16x32_bf16(a1, b1, acc[1][1], 0, 0, 0);
        acc[1][2] = __builtin_amdgcn_mfma_f32_16x16x32_bf16(a1, b2, acc[1][2], 0, 0, 0);
        acc[1][3] = __builtin_amdgcn_mfma_f32_16x16x32_bf16(a1, b3, acc[1][3], 0, 0, 0);
        acc[2][0] = __builtin_amdgcn_mfma_f32_16x16x32_bf16(a2, b0, acc[2][0], 0, 0, 0);
        acc[2][1] = __builtin_amdgcn_mfma_f32_16x16x32_bf16(a2, b1, acc[2][1], 0, 0, 0);
        acc[2][2] = __builtin_amdgcn_mfma_f32_16x16x32_bf16(a2, b2, acc[2][2], 0, 0, 0);
        acc[2][3] = __builtin_amdgcn_mfma_f32_16x16x32_bf16(a2, b3, acc[2][3], 0, 0, 0);
        acc[3][0] = __builtin_amdgcn_mfma_f32_16x16x32_bf16(a3, b0, acc[3][0], 0, 0, 0);
        acc[3][1] = __builtin_amdgcn_mfma_f32_16x16x32_bf16(a3, b1, acc[3][1], 0, 0, 0);
        acc[3][2] = __builtin_amdgcn_mfma_f32_16x16x32_bf16(a3, b2, acc[3][2], 0, 0, 0);
        acc[3][3] = __builtin_amdgcn_mfma_f32_16x16x32_bf16(a3, b3, acc[3][3], 0, 0, 0);
        __syncthreads();                 // compute done before next overwrite
    }

    const int fq = lane >> 4;
#pragma unroll
    for (int nj = 0; nj < 4; nj++) {
        int n = n0 + wc * 64 + nj * 16 + fr;
        if (EPI == 0) {
            float bias = (n < NH) ? biasL[n] : biasR[n - NH];
            bool left = (n < NH);
            int nn = left ? n : (n - NH);
            u16* Out = (u16*)OutBase;
#pragma unroll
            for (int mi = 0; mi < 4; mi++) {
                int mb = m0 + wr * 64 + mi * 16 + fq * 4;
#pragma unroll
                for (int r = 0; r < 4; r++) {
                    float val = fmaxf(acc[mi][nj][r] + bias, 0.f);
                    u16 h = f2bf(val);
                    u16 lo = f2bf(val - bf2f(h));
                    size_t rb = (size_t)(mb + r) * (4 * (size_t)NH);
                    if (left) { Out[rb + nn] = h; Out[rb + NH + nn] = lo; }
                    else { Out[rb + 2 * (size_t)NH + nn] = h; Out[rb + 3 * (size_t)NH + nn] = lo; }
                }
            }
        } else {
            float* Out = (float*)OutBase + (size_t)z * out_z_stride;
#pragma unroll
            for (int mi = 0; mi < 4; mi++) {
                int mb = m0 + wr * 64 + mi * 16 + fq * 4;
#pragma unroll
                for (int r = 0; r < 4; r++)
                    Out[(size_t)(mb + r) * (2 * (size_t)NH) + n] = acc[mi][nj][r];
            }
        }
    }
}

// ---------------------------------------------------------------------------
// Router: amp = sqrt((c2a+c2b+b2r)^2 + (...)^2); logits; top-3; softmax; scatter
// ---------------------------------------------------------------------------
__global__ __launch_bounds__(128) void router_kernel(
    const float* __restrict__ c2a, const float* __restrict__ c2b,
    const float* __restrict__ b2,
    const float* __restrict__ w_gate, const float* __restrict__ w_noise,
    const float* __restrict__ noise_z, float* __restrict__ gates)
{
    __shared__ float s_amp[1024];
    __shared__ float s_logit[P_DIM];
    __shared__ int   s_idx[3];
    __shared__ float s_val[3];

    int b = blockIdx.x;
    const float* ra = c2a + (size_t)b * 2048;
    const float* rb = c2b + (size_t)b * 2048;
    for (int i = threadIdx.x; i < 1024; i += 128) {
        float orr = ra[i] + rb[i] + b2[i];
        float oii = ra[1024 + i] + rb[1024 + i] + b2[1024 + i];
        s_amp[i] = sqrtf(orr * orr + oii * oii);
    }
    __syncthreads();

    int p = threadIdx.x;
    if (p < P_DIM) {
        float cg = 0.f, cn = 0.f;
        for (int k = 0; k < 1024; k++) {
            float a = s_amp[k];
            cg = fmaf(a, w_gate[k * P_DIM + p], cg);
            cn = fmaf(a, w_noise[k * P_DIM + p], cn);
        }
        float ns = (cn > 20.f) ? cn : log1pf(expf(cn));
        ns += 0.01f;
        s_logit[p] = cg + noise_z[(size_t)b * P_DIM + p] * ns;
    }
    __syncthreads();

    if (threadIdx.x == 0) {
        int i0 = -1, i1 = -1, i2 = -1;
        float v0 = -1e30f, v1 = -1e30f, v2 = -1e30f;
        for (int i = 0; i < P_DIM; i++) {
            float t = s_logit[i];
            if (t > v0) { v0 = t; i0 = i; }
        }
        for (int i = 0; i < P_DIM; i++) {
            if (i == i0) continue;
            float t = s_logit[i];
            if (t > v1) { v1 = t; i1 = i; }
        }
        for (int i = 0; i < P_DIM; i++) {
            if (i == i0 || i == i1) continue;
            float t = s_logit[i];
            if (t > v2) { v2 = t; i2 = i; }
        }
        s_idx[0] = i0; s_idx[1] = i1; s_idx[2] = i2;
        s_val[0] = v0; s_val[1] = v1; s_val[2] = v2;
    }
    __syncthreads();

    if (p < P_DIM) {
        float m = s_val[0];
        float e0 = expf(s_val[0] - m);
        float e1 = expf(s_val[1] - m);
        float e2 = expf(s_val[2] - m);
        float inv = 1.f / (e0 + e1 + e2);
        float g = 0.f;
        if (p == s_idx[0]) g = e0 * inv;
        else if (p == s_idx[1]) g = e1 * inv;
        else if (p == s_idx[2]) g = e2 * inv;
        gates[(size_t)b * P_DIM + p] = g;
    }
}

// ---------------------------------------------------------------------------
extern "C" void kernel_launch(void* const* d_in, const int* in_sizes, int n_in,
                              void* d_out, int out_size, void* d_ws, size_t ws_size,
                              hipStream_t stream)
{
    const float* x       = (const float*)d_in[0];
    const float* w_start = (const float*)d_in[1];
    const float* b_start = (const float*)d_in[2];
    const float* w1      = (const float*)d_in[3];  // [2, F, H]
    const float* b1      = (const float*)d_in[4];  // [2, H]
    const float* w2      = (const float*)d_in[5];  // [2, H, F]
    const float* b2      = (const float*)d_in[6];  // [2, F]
    const float* w_gate  = (const float*)d_in[7];
    const float* w_noise = (const float*)d_in[8];
    const float* noise_z = (const float*)d_in[9];
    float* gates = (float*)d_out;

    const size_t MB = 1024 * 1024;
    char* base = (char*)d_ws;
    float* v   = (float*)base;                       // [2048][2048] f32, reused as C2a
    u16*  A1   = (u16*)(base + 16 * MB);             // [2048][4096], reused as C2b
    u16*  BT   = (u16*)(base + 32 * MB);             // up to [8192][4096] bf16
    u16*  A2   = (u16*)(base + 96 * MB);             // [2048][16384] bf16
    float* C2a = v;
    float* C2b = (float*)(base + 16 * MB);

    start_fc_kernel<<<(B_DIM * L_DIM) / 256, 256, 0, stream>>>(x, w_start, b_start, v);
    fft_kernel<<<B_DIM, 256, 0, stream>>>(v, A1);

    // layer 1: Kc=1024 (F), Nh=4096 (H)
    conv_bt_kernel<<<dim3(F_DIM / 32, H_DIM / 32), dim3(32, 8), 0, stream>>>(
        w1, BT, F_DIM, H_DIM);
    gemm_split<0><<<dim3(2 * H_DIM / 128, B_DIM / 128, 1), 256, 0, stream>>>(
        A1, BT, b1, b1 + H_DIM, A2, F_DIM, 10, H_DIM, 6 * F_DIM / 32, 0);

    // layer 2: Kc=4096 (H), Nh=1024 (F); split-K z=2
    conv_bt_kernel<<<dim3(H_DIM / 32, F_DIM / 32), dim3(32, 8), 0, stream>>>(
        w2, BT, H_DIM, F_DIM);
    gemm_split<1><<<dim3(2 * F_DIM / 128, B_DIM / 128, 2), 256, 0, stream>>>(
        A2, BT, b2, b2 + F_DIM, C2a, H_DIM, 12, F_DIM, 6 * H_DIM / 32 / 2,
        (size_t)B_DIM * 2048);

    router_kernel<<<B_DIM, 128, 0, stream>>>(
        C2a, C2b, b2, w_gate, w_noise, noise_z, gates);
}

// Round 3
// 633.305 us; speedup vs baseline: 4.8711x; 1.1979x over previous
//
#include <hip/hip_runtime.h>
#include <hip/hip_bf16.h>
#include <math.h>

#define B_DIM 2048
#define L_DIM 2048
#define F_DIM 1024
#define H_DIM 4096
#define P_DIM 88

typedef unsigned short u16;
typedef short bf16x8 __attribute__((ext_vector_type(8)));
typedef float f32x4 __attribute__((ext_vector_type(4)));

// ---- bf16 split helpers (RNE) ----
__device__ __forceinline__ u16 f2bf(float x) {
    unsigned u = __float_as_uint(x);
    return (u16)((u + 0x7fffu + ((u >> 16) & 1u)) >> 16);
}
__device__ __forceinline__ float bf2f(u16 h) {
    return __uint_as_float(((unsigned)h) << 16);
}

// ---- async global->LDS, 16B per lane (dest = wave-uniform base + lane*16) ----
__device__ __forceinline__ void gload_lds16(const void* g, void* l) {
    unsigned loff = (unsigned)(uintptr_t)l;
    __builtin_amdgcn_global_load_lds(
        reinterpret_cast<const __attribute__((address_space(1))) void*>(
            reinterpret_cast<uintptr_t>(g)),
        reinterpret_cast<__attribute__((address_space(3))) void*>(loff),
        16, 0, 0);
}

// ---------------------------------------------------------------------------
// start_fc
// ---------------------------------------------------------------------------
__global__ __launch_bounds__(256) void start_fc_kernel(
    const float* __restrict__ x, const float* __restrict__ w_start,
    const float* __restrict__ b_start, float* __restrict__ v)
{
    size_t gid = (size_t)blockIdx.x * 256 + threadIdx.x;
    const float4* xp = (const float4*)(x + gid * 16);
    const float4* wp = (const float4*)w_start;
    float acc = b_start[0];
#pragma unroll
    for (int q = 0; q < 4; q++) {
        float4 xv = xp[q];
        float4 wv = wp[q];
        acc += xv.x * wv.x + xv.y * wv.y + xv.z * wv.z + xv.w * wv.w;
    }
    v[gid] = acc;
}

// ---------------------------------------------------------------------------
// 2048-pt FFT per row -> A1 phys segments [xr_h | xr_l | xi_h | xi_l]
// ---------------------------------------------------------------------------
__global__ __launch_bounds__(256) void fft_kernel(
    const float* __restrict__ v, u16* __restrict__ A1)
{
    __shared__ float re[2048];
    __shared__ float im[2048];
    int b = blockIdx.x;
    const float* row = v + (size_t)b * 2048;

    for (int i = threadIdx.x; i < 2048; i += 256) {
        unsigned j = __brev((unsigned)i) >> 21;
        re[i] = row[j];
        im[i] = 0.f;
    }
    __syncthreads();

    for (int s = 1; s <= 11; s++) {
        int half = 1 << (s - 1);
        for (int t = threadIdx.x; t < 1024; t += 256) {
            int j = t & (half - 1);
            int base = (t >> (s - 1)) << s;
            float ang = -6.283185307179586f * (float)j / (float)(1 << s);
            float wr, wi;
            sincosf(ang, &wi, &wr);
            int i0 = base + j, i1 = i0 + half;
            float br = re[i1], bi = im[i1];
            float tr = br * wr - bi * wi;
            float ti = br * wi + bi * wr;
            float ar = re[i0], ai = im[i0];
            re[i0] = ar + tr; im[i0] = ai + ti;
            re[i1] = ar - tr; im[i1] = ai - ti;
        }
        __syncthreads();
    }

    const float sc = 0.022097086912079612f;  // 1/sqrt(2048)
    u16* arow = A1 + (size_t)b * 4096;
    for (int t = threadIdx.x; t < 1024; t += 256) {
        float r = re[t + 1] * sc;
        float q = im[t + 1] * sc;
        u16 rh = f2bf(r); u16 rl = f2bf(r - bf2f(rh));
        u16 ih = f2bf(q); u16 il = f2bf(q - bf2f(ih));
        arow[t] = rh; arow[1024 + t] = rl;
        arow[2048 + t] = ih; arow[3072 + t] = il;
    }
}

// ---------------------------------------------------------------------------
// Weight conversion w[2][Kc][Nh] fp32 -> BT [2*Nh][4*Kc] bf16 (transposed, split)
// ---------------------------------------------------------------------------
__global__ __launch_bounds__(256) void conv_bt_kernel(
    const float* __restrict__ w, u16* __restrict__ BT, int Kc, int Nh)
{
    __shared__ float t0[32][33];
    __shared__ float t1[32][33];
    int k0 = blockIdx.x * 32, n0 = blockIdx.y * 32;
    int tx = threadIdx.x, ty = threadIdx.y;     // (32, 8)
    const float* w0 = w;
    const float* w1 = w + (size_t)Kc * Nh;

#pragma unroll
    for (int i = 0; i < 4; i++) {
        int k = k0 + ty + 8 * i;
        t0[ty + 8 * i][tx] = w0[(size_t)k * Nh + n0 + tx];
        t1[ty + 8 * i][tx] = w1[(size_t)k * Nh + n0 + tx];
    }
    __syncthreads();

    size_t K4 = 4 * (size_t)Kc;
    int k = k0 + tx;
#pragma unroll
    for (int i = 0; i < 4; i++) {
        int nl = ty + 8 * i;
        int n = n0 + nl;
        float br = t0[tx][nl];
        float bi = t1[tx][nl];
        u16 brh = f2bf(br); u16 brl = f2bf(br - bf2f(brh));
        float nbi = -bi;
        u16 nih = f2bf(nbi); u16 nil = f2bf(nbi - bf2f(nih));
        u16 pih = f2bf(bi);  u16 pil = f2bf(bi - bf2f(pih));
        u16* rowr = BT + (size_t)n * K4;
        rowr[0 * Kc + k] = brh; rowr[1 * Kc + k] = brl;
        rowr[2 * Kc + k] = nih; rowr[3 * Kc + k] = nil;
        u16* rowi = BT + (size_t)(Nh + n) * K4;
        rowi[0 * Kc + k] = pih; rowi[1 * Kc + k] = pil;
        rowi[2 * Kc + k] = brh; rowi[3 * Kc + k] = brl;
    }
}

// ---------------------------------------------------------------------------
// 8-phase-style deep-pipelined split-bf16 GEMM.
// 256x256 tile, BK=32, 8 waves (2M x 4N), ring of 4 LDS slots per operand.
// Stage tile t+2 while computing tile t; counted vmcnt(4); raw s_barrier.
// T2 swizzle: chunk ^= (row>>1)&3, via pre-swizzled global source.
// EPI=0: relu(acc+bias) -> split-bf16 A2 phys layout. SWZ=1: XCD-chunked grid.
// EPI=1: raw fp32 partial (split-K z), summed in router.
// ---------------------------------------------------------------------------
extern __shared__ char smem8p[];

template <int EPI, int SWZ>
__global__ __launch_bounds__(512, 2) void gemm8p(
    const u16* __restrict__ A, const u16* __restrict__ B,
    const float* __restrict__ biasL, const float* __restrict__ biasR,
    u16* __restrict__ OutU, float* __restrict__ P01, float* __restrict__ P23,
    int Kc, int KcLog, int NH, int nt)
{
    char* ldsA = smem8p;              // 4 slots x 16384 B  (A tile 256x32 bf16)
    char* ldsB = smem8p + 65536;      // 4 slots x 16384 B

    const int tid = threadIdx.x;
    const int w = tid >> 6, lane = tid & 63;
    const int wr = w >> 2, wc = w & 3;           // 2M x 4N waves
    const int fr = lane & 15, kb = lane >> 4;

    int bx, by, z;
    if (SWZ) {
        int b = blockIdx.x;
        int xcd = b & 7, idx = b >> 3;
        bx = 4 * xcd + (idx & 3);                // 32 N-blocks
        by = idx >> 2;                           // 8 M-blocks
        z = 0;
    } else {
        bx = blockIdx.x; by = blockIdx.y; z = blockIdx.z;
    }
    const int n0 = bx * 256, m0 = by * 256;
    const size_t K4 = 4 * (size_t)Kc;

    // staging constants: thread covers row srow(+128), swizzled source chunk
    const int srow = tid >> 2;
    const int lk8 = (((tid & 3) ^ ((tid >> 3) & 3))) * 8;   // element offset
    const int wb = (tid >> 6) * 1024;                       // wave dest base (B)

    // frag read lane offset (bytes): row fr, chunk kb ^ ((fr>>1)&3)
    const int laneOff = fr * 64 + ((kb ^ ((fr >> 1) & 3)) << 4);

    f32x4 acc[8][4];
#pragma unroll
    for (int i = 0; i < 8; i++)
#pragma unroll
        for (int j = 0; j < 4; j++)
            acc[i][j] = (f32x4){0.f, 0.f, 0.f, 0.f};

    const int t0 = z * nt, te = t0 + nt;

    auto colA = [&](int t) {
        int k0 = t << 5;
        int seg = k0 >> KcLog, kk = k0 & (Kc - 1);
        int r3 = seg >= 3 ? seg - 3 : seg;
        int bs = seg >= 3 ? 2 : 0;
        return (bs + (r3 == 1 ? 1 : 0)) * Kc + kk;
    };
    auto colB = [&](int t) {
        int k0 = t << 5;
        int seg = k0 >> KcLog, kk = k0 & (Kc - 1);
        int r3 = seg >= 3 ? seg - 3 : seg;
        int bs = seg >= 3 ? 2 : 0;
        return (bs + (r3 == 2 ? 1 : 0)) * Kc + kk;
    };
    auto stageA = [&](int t) {
        const u16* src = A + (size_t)(m0 + srow) * K4 + colA(t) + lk8;
        char* dst = ldsA + (t & 3) * 16384 + wb;
        gload_lds16(src, dst);
        gload_lds16(src + (size_t)128 * K4, dst + 8192);
    };
    auto stageB = [&](int t) {
        const u16* src = B + (size_t)(n0 + srow) * K4 + colB(t) + lk8;
        char* dst = ldsB + (t & 3) * 16384 + wb;
        gload_lds16(src, dst);
        gload_lds16(src + (size_t)128 * K4, dst + 8192);
    };

    // prologue: tiles t0, t0+1 in flight
    stageA(t0); stageB(t0);
    if (t0 + 1 < te) { stageA(t0 + 1); stageB(t0 + 1); }

    for (int t = t0; t < te; ++t) {
        if (t + 1 < te) asm volatile("s_waitcnt vmcnt(4)" ::: "memory");
        else            asm volatile("s_waitcnt vmcnt(0)" ::: "memory");
        asm volatile("s_barrier" ::: "memory");

        const int slot = t & 3;
        const char* aS = ldsA + slot * 16384 + wr * 8192 + laneOff;  // wr*128 rows
        const char* bS = ldsB + slot * 16384 + wc * 4096 + laneOff;  // wc*64 rows

        // ---- phase 1: M-half 0 ----
        bf16x8 b0 = *(const bf16x8*)(bS + 0 * 1024);
        bf16x8 b1 = *(const bf16x8*)(bS + 1 * 1024);
        bf16x8 b2 = *(const bf16x8*)(bS + 2 * 1024);
        bf16x8 b3 = *(const bf16x8*)(bS + 3 * 1024);
        bf16x8 a0 = *(const bf16x8*)(aS + 0 * 1024);
        bf16x8 a1 = *(const bf16x8*)(aS + 1 * 1024);
        bf16x8 a2 = *(const bf16x8*)(aS + 2 * 1024);
        bf16x8 a3 = *(const bf16x8*)(aS + 3 * 1024);
        if (t + 2 < te) stageA(t + 2);

        __builtin_amdgcn_s_setprio(1);
        acc[0][0] = __builtin_amdgcn_mfma_f32_16x16x32_bf16(a0, b0, acc[0][0], 0, 0, 0);
        acc[0][1] = __builtin_amdgcn_mfma_f32_16x16x32_bf16(a0, b1, acc[0][1], 0, 0, 0);
        acc[0][2] = __builtin_amdgcn_mfma_f32_16x16x32_bf16(a0, b2, acc[0][2], 0, 0, 0);
        acc[0][3] = __builtin_amdgcn_mfma_f32_16x16x32_bf16(a0, b3, acc[0][3], 0, 0, 0);
        acc[1][0] = __builtin_amdgcn_mfma_f32_16x16x32_bf16(a1, b0, acc[1][0], 0, 0, 0);
        acc[1][1] = __builtin_amdgcn_mfma_f32_16x16x32_bf16(a1, b1, acc[1][1], 0, 0, 0);
        acc[1][2] = __builtin_amdgcn_mfma_f32_16x16x32_bf16(a1, b2, acc[1][2], 0, 0, 0);
        acc[1][3] = __builtin_amdgcn_mfma_f32_16x16x32_bf16(a1, b3, acc[1][3], 0, 0, 0);
        acc[2][0] = __builtin_amdgcn_mfma_f32_16x16x32_bf16(a2, b0, acc[2][0], 0, 0, 0);
        acc[2][1] = __builtin_amdgcn_mfma_f32_16x16x32_bf16(a2, b1, acc[2][1], 0, 0, 0);
        acc[2][2] = __builtin_amdgcn_mfma_f32_16x16x32_bf16(a2, b2, acc[2][2], 0, 0, 0);
        acc[2][3] = __builtin_amdgcn_mfma_f32_16x16x32_bf16(a2, b3, acc[2][3], 0, 0, 0);
        acc[3][0] = __builtin_amdgcn_mfma_f32_16x16x32_bf16(a3, b0, acc[3][0], 0, 0, 0);
        acc[3][1] = __builtin_amdgcn_mfma_f32_16x16x32_bf16(a3, b1, acc[3][1], 0, 0, 0);
        acc[3][2] = __builtin_amdgcn_mfma_f32_16x16x32_bf16(a3, b2, acc[3][2], 0, 0, 0);
        acc[3][3] = __builtin_amdgcn_mfma_f32_16x16x32_bf16(a3, b3, acc[3][3], 0, 0, 0);
        __builtin_amdgcn_s_setprio(0);
        asm volatile("s_barrier" ::: "memory");

        // ---- phase 2: M-half 1 ----
        a0 = *(const bf16x8*)(aS + 4096 + 0 * 1024);
        a1 = *(const bf16x8*)(aS + 4096 + 1 * 1024);
        a2 = *(const bf16x8*)(aS + 4096 + 2 * 1024);
        a3 = *(const bf16x8*)(aS + 4096 + 3 * 1024);
        if (t + 2 < te) stageB(t + 2);

        __builtin_amdgcn_s_setprio(1);
        acc[4][0] = __builtin_amdgcn_mfma_f32_16x16x32_bf16(a0, b0, acc[4][0], 0, 0, 0);
        acc[4][1] = __builtin_amdgcn_mfma_f32_16x16x32_bf16(a0, b1, acc[4][1], 0, 0, 0);
        acc[4][2] = __builtin_amdgcn_mfma_f32_16x16x32_bf16(a0, b2, acc[4][2], 0, 0, 0);
        acc[4][3] = __builtin_amdgcn_mfma_f32_16x16x32_bf16(a0, b3, acc[4][3], 0, 0, 0);
        acc[5][0] = __builtin_amdgcn_mfma_f32_16x16x32_bf16(a1, b0, acc[5][0], 0, 0, 0);
        acc[5][1] = __builtin_amdgcn_mfma_f32_16x16x32_bf16(a1, b1, acc[5][1], 0, 0, 0);
        acc[5][2] = __builtin_amdgcn_mfma_f32_16x16x32_bf16(a1, b2, acc[5][2], 0, 0, 0);
        acc[5][3] = __builtin_amdgcn_mfma_f32_16x16x32_bf16(a1, b3, acc[5][3], 0, 0, 0);
        acc[6][0] = __builtin_amdgcn_mfma_f32_16x16x32_bf16(a2, b0, acc[6][0], 0, 0, 0);
        acc[6][1] = __builtin_amdgcn_mfma_f32_16x16x32_bf16(a2, b1, acc[6][1], 0, 0, 0);
        acc[6][2] = __builtin_amdgcn_mfma_f32_16x16x32_bf16(a2, b2, acc[6][2], 0, 0, 0);
        acc[6][3] = __builtin_amdgcn_mfma_f32_16x16x32_bf16(a2, b3, acc[6][3], 0, 0, 0);
        acc[7][0] = __builtin_amdgcn_mfma_f32_16x16x32_bf16(a3, b0, acc[7][0], 0, 0, 0);
        acc[7][1] = __builtin_amdgcn_mfma_f32_16x16x32_bf16(a3, b1, acc[7][1], 0, 0, 0);
        acc[7][2] = __builtin_amdgcn_mfma_f32_16x16x32_bf16(a3, b2, acc[7][2], 0, 0, 0);
        acc[7][3] = __builtin_amdgcn_mfma_f32_16x16x32_bf16(a3, b3, acc[7][3], 0, 0, 0);
        __builtin_amdgcn_s_setprio(0);
    }

    // ---- epilogue ----
    const int fq = kb;
#pragma unroll
    for (int nj = 0; nj < 4; nj++) {
        int n = n0 + wc * 64 + nj * 16 + fr;
        if (EPI == 0) {
            bool left = (n < NH);
            int nn = left ? n : (n - NH);
            float bias = left ? biasL[n] : biasR[nn];
#pragma unroll
            for (int mi = 0; mi < 8; mi++) {
                int mb = m0 + wr * 128 + mi * 16 + fq * 4;
#pragma unroll
                for (int r = 0; r < 4; r++) {
                    float val = fmaxf(acc[mi][nj][r] + bias, 0.f);
                    u16 h = f2bf(val);
                    u16 lo = f2bf(val - bf2f(h));
                    size_t rb = (size_t)(mb + r) * (4 * (size_t)NH);
                    if (left) { OutU[rb + nn] = h; OutU[rb + NH + nn] = lo; }
                    else { OutU[rb + 2 * (size_t)NH + nn] = h; OutU[rb + 3 * (size_t)NH + nn] = lo; }
                }
            }
        } else {
            const size_t PSZ = (size_t)2048 * 2048;
            float* Out = (z < 2) ? (P01 + (size_t)z * PSZ) : (P23 + (size_t)(z - 2) * PSZ);
#pragma unroll
            for (int mi = 0; mi < 8; mi++) {
                int mb = m0 + wr * 128 + mi * 16 + fq * 4;
#pragma unroll
                for (int r = 0; r < 4; r++)
                    Out[(size_t)(mb + r) * 2048 + n] = acc[mi][nj][r];
            }
        }
    }
}

// ---------------------------------------------------------------------------
// Router: sum split-K partials + bias -> amp -> logits -> top-3 -> gates
// ---------------------------------------------------------------------------
__global__ __launch_bounds__(128) void router_kernel(
    const float* __restrict__ P01, const float* __restrict__ P23, int ZK,
    const float* __restrict__ b2,
    const float* __restrict__ w_gate, const float* __restrict__ w_noise,
    const float* __restrict__ noise_z, float* __restrict__ gates)
{
    __shared__ float s_amp[1024];
    __shared__ float s_logit[P_DIM];
    __shared__ int   s_idx[3];
    __shared__ float s_val[3];

    int b = blockIdx.x;
    const size_t PSZ = (size_t)2048 * 2048;
    const size_t roff = (size_t)b * 2048;

    for (int i = threadIdx.x; i < 1024; i += 128) {
        float orr = b2[i];
        float oii = b2[1024 + i];
        for (int zz = 0; zz < ZK; zz++) {
            const float* Pz = ((zz < 2) ? (P01 + (size_t)zz * PSZ)
                                        : (P23 + (size_t)(zz - 2) * PSZ)) + roff;
            orr += Pz[i];
            oii += Pz[1024 + i];
        }
        s_amp[i] = sqrtf(orr * orr + oii * oii);
    }
    __syncthreads();

    int p = threadIdx.x;
    if (p < P_DIM) {
        float cg = 0.f, cn = 0.f;
        for (int k = 0; k < 1024; k++) {
            float a = s_amp[k];
            cg = fmaf(a, w_gate[k * P_DIM + p], cg);
            cn = fmaf(a, w_noise[k * P_DIM + p], cn);
        }
        float ns = (cn > 20.f) ? cn : log1pf(expf(cn));
        ns += 0.01f;
        s_logit[p] = cg + noise_z[(size_t)b * P_DIM + p] * ns;
    }
    __syncthreads();

    if (threadIdx.x == 0) {
        int i0 = -1, i1 = -1, i2 = -1;
        float v0 = -1e30f, v1 = -1e30f, v2 = -1e30f;
        for (int i = 0; i < P_DIM; i++) {
            float t = s_logit[i];
            if (t > v0) { v0 = t; i0 = i; }
        }
        for (int i = 0; i < P_DIM; i++) {
            if (i == i0) continue;
            float t = s_logit[i];
            if (t > v1) { v1 = t; i1 = i; }
        }
        for (int i = 0; i < P_DIM; i++) {
            if (i == i0 || i == i1) continue;
            float t = s_logit[i];
            if (t > v2) { v2 = t; i2 = i; }
        }
        s_idx[0] = i0; s_idx[1] = i1; s_idx[2] = i2;
        s_val[0] = v0; s_val[1] = v1; s_val[2] = v2;
    }
    __syncthreads();

    if (p < P_DIM) {
        float m = s_val[0];
        float e0 = expf(s_val[0] - m);
        float e1 = expf(s_val[1] - m);
        float e2 = expf(s_val[2] - m);
        float inv = 1.f / (e0 + e1 + e2);
        float g = 0.f;
        if (p == s_idx[0]) g = e0 * inv;
        else if (p == s_idx[1]) g = e1 * inv;
        else if (p == s_idx[2]) g = e2 * inv;
        gates[(size_t)b * P_DIM + p] = g;
    }
}

// ---------------------------------------------------------------------------
extern "C" void kernel_launch(void* const* d_in, const int* in_sizes, int n_in,
                              void* d_out, int out_size, void* d_ws, size_t ws_size,
                              hipStream_t stream)
{
    const float* x       = (const float*)d_in[0];
    const float* w_start = (const float*)d_in[1];
    const float* b_start = (const float*)d_in[2];
    const float* w1      = (const float*)d_in[3];
    const float* b1      = (const float*)d_in[4];
    const float* w2      = (const float*)d_in[5];
    const float* b2      = (const float*)d_in[6];
    const float* w_gate  = (const float*)d_in[7];
    const float* w_noise = (const float*)d_in[8];
    const float* noise_z = (const float*)d_in[9];
    float* gates = (float*)d_out;

    const size_t MB = 1024 * 1024;
    char* base = (char*)d_ws;
    float* v   = (float*)base;               // [0,16) MB — dead after fft
    u16*  A1   = (u16*)(base + 16 * MB);     // [16,32) — dead after gemm1
    u16*  BT   = (u16*)(base + 32 * MB);     // [32,96) — BT1 then BT2
    u16*  A2   = (u16*)(base + 96 * MB);     // [96,160)
    float* P01 = (float*)base;               // partials z0,z1 -> [0,32)
    float* P23 = (float*)(base + 160 * MB);  // partials z2,z3 -> [160,192)

    // split-K factor for layer 2: z=4 needs 192 MB of workspace
    int ZK = (ws_size >= (size_t)192 * MB) ? 4 : 2;

    hipFuncSetAttribute(reinterpret_cast<const void*>(&gemm8p<0, 1>),
                        hipFuncAttributeMaxDynamicSharedMemorySize, 131072);
    hipFuncSetAttribute(reinterpret_cast<const void*>(&gemm8p<1, 0>),
                        hipFuncAttributeMaxDynamicSharedMemorySize, 131072);

    start_fc_kernel<<<(B_DIM * L_DIM) / 256, 256, 0, stream>>>(x, w_start, b_start, v);
    fft_kernel<<<B_DIM, 256, 0, stream>>>(v, A1);

    // layer 1: M=2048, N=8192, Kc=1024 (K_eff=6144, nt=192); XCD-swizzled grid
    conv_bt_kernel<<<dim3(F_DIM / 32, H_DIM / 32), dim3(32, 8), 0, stream>>>(
        w1, BT, F_DIM, H_DIM);
    gemm8p<0, 1><<<256, 512, 131072, stream>>>(
        A1, BT, b1, b1 + H_DIM, A2, nullptr, nullptr, F_DIM, 10, H_DIM, 192);

    // layer 2: M=2048, N=2048, Kc=4096 (K_eff=24576, nt_total=768), split-K ZK
    conv_bt_kernel<<<dim3(H_DIM / 32, F_DIM / 32), dim3(32, 8), 0, stream>>>(
        w2, BT, H_DIM, F_DIM);
    gemm8p<1, 0><<<dim3(8, 8, ZK), 512, 131072, stream>>>(
        A2, BT, nullptr, nullptr, nullptr, P01, P23, H_DIM, 12, F_DIM, 768 / ZK);

    router_kernel<<<B_DIM, 128, 0, stream>>>(
        P01, P23, ZK, b2, w_gate, w_noise, noise_z, gates);
}

// Round 4
// 595.492 us; speedup vs baseline: 5.1804x; 1.0635x over previous
//
#include <hip/hip_runtime.h>
#include <hip/hip_bf16.h>
#include <math.h>

#define B_DIM 2048
#define L_DIM 2048
#define F_DIM 1024
#define H_DIM 4096
#define P_DIM 88

typedef unsigned short u16;
typedef short bf16x8 __attribute__((ext_vector_type(8)));
typedef float f32x4 __attribute__((ext_vector_type(4)));

// ---- bf16 split helpers (RNE) ----
__device__ __forceinline__ u16 f2bf(float x) {
    unsigned u = __float_as_uint(x);
    return (u16)((u + 0x7fffu + ((u >> 16) & 1u)) >> 16);
}
__device__ __forceinline__ float bf2f(u16 h) {
    return __uint_as_float(((unsigned)h) << 16);
}

// ---- async global->LDS, 16B per lane (dest = wave-uniform base + lane*16) ----
__device__ __forceinline__ void gload_lds16(const void* g, void* l) {
    unsigned loff = (unsigned)(uintptr_t)l;
    __builtin_amdgcn_global_load_lds(
        reinterpret_cast<const __attribute__((address_space(1))) void*>(
            reinterpret_cast<uintptr_t>(g)),
        reinterpret_cast<__attribute__((address_space(3))) void*>(loff),
        16, 0, 0);
}

// ---------------------------------------------------------------------------
// Fused start_fc + 2048-pt FFT per row -> A1 [xr_h | xr_l | xi_h | xi_l]
// ---------------------------------------------------------------------------
__global__ __launch_bounds__(256) void fft_kernel(
    const float* __restrict__ x, const float* __restrict__ w_start,
    const float* __restrict__ b_start, u16* __restrict__ A1)
{
    __shared__ float re[2048];
    __shared__ float im[2048];
    int b = blockIdx.x;

    const float4* wp = (const float4*)w_start;
    float4 w0 = wp[0], w1 = wp[1], w2 = wp[2], w3 = wp[3];
    float bs = b_start[0];

    for (int l = threadIdx.x; l < 2048; l += 256) {
        const float4* xp = (const float4*)(x + ((size_t)b * 2048 + l) * 16);
        float4 x0 = xp[0], x1 = xp[1], x2 = xp[2], x3 = xp[3];
        float acc = bs;
        acc += x0.x * w0.x + x0.y * w0.y + x0.z * w0.z + x0.w * w0.w;
        acc += x1.x * w1.x + x1.y * w1.y + x1.z * w1.z + x1.w * w1.w;
        acc += x2.x * w2.x + x2.y * w2.y + x2.z * w2.z + x2.w * w2.w;
        acc += x3.x * w3.x + x3.y * w3.y + x3.z * w3.z + x3.w * w3.w;
        unsigned j = __brev((unsigned)l) >> 21;   // bit-reversed position
        re[j] = acc;
        im[j] = 0.f;
    }
    __syncthreads();

    for (int s = 1; s <= 11; s++) {
        int half = 1 << (s - 1);
        for (int t = threadIdx.x; t < 1024; t += 256) {
            int j = t & (half - 1);
            int base = (t >> (s - 1)) << s;
            float ang = -6.283185307179586f * (float)j / (float)(1 << s);
            float wr, wi;
            sincosf(ang, &wi, &wr);
            int i0 = base + j, i1 = i0 + half;
            float br = re[i1], bi = im[i1];
            float tr = br * wr - bi * wi;
            float ti = br * wi + bi * wr;
            float ar = re[i0], ai = im[i0];
            re[i0] = ar + tr; im[i0] = ai + ti;
            re[i1] = ar - tr; im[i1] = ai - ti;
        }
        __syncthreads();
    }

    const float sc = 0.022097086912079612f;  // 1/sqrt(2048)
    u16* arow = A1 + (size_t)b * 4096;
    for (int t = threadIdx.x; t < 1024; t += 256) {
        float r = re[t + 1] * sc;
        float q = im[t + 1] * sc;
        u16 rh = f2bf(r); u16 rl = f2bf(r - bf2f(rh));
        u16 ih = f2bf(q); u16 il = f2bf(q - bf2f(ih));
        arow[t] = rh; arow[1024 + t] = rl;
        arow[2048 + t] = ih; arow[3072 + t] = il;
    }
}

// ---------------------------------------------------------------------------
// Weight conversion w[2][Kc][Nh] fp32 -> BT [2*Nh][4*Kc] bf16 (transposed, split)
// ---------------------------------------------------------------------------
__global__ __launch_bounds__(256) void conv_bt_kernel(
    const float* __restrict__ w, u16* __restrict__ BT, int Kc, int Nh)
{
    __shared__ float t0[32][33];
    __shared__ float t1[32][33];
    int k0 = blockIdx.x * 32, n0 = blockIdx.y * 32;
    int tx = threadIdx.x, ty = threadIdx.y;     // (32, 8)
    const float* w0 = w;
    const float* w1 = w + (size_t)Kc * Nh;

#pragma unroll
    for (int i = 0; i < 4; i++) {
        int k = k0 + ty + 8 * i;
        t0[ty + 8 * i][tx] = w0[(size_t)k * Nh + n0 + tx];
        t1[ty + 8 * i][tx] = w1[(size_t)k * Nh + n0 + tx];
    }
    __syncthreads();

    size_t K4 = 4 * (size_t)Kc;
    int k = k0 + tx;
#pragma unroll
    for (int i = 0; i < 4; i++) {
        int nl = ty + 8 * i;
        int n = n0 + nl;
        float br = t0[tx][nl];
        float bi = t1[tx][nl];
        u16 brh = f2bf(br); u16 brl = f2bf(br - bf2f(brh));
        float nbi = -bi;
        u16 nih = f2bf(nbi); u16 nil = f2bf(nbi - bf2f(nih));
        u16 pih = f2bf(bi);  u16 pil = f2bf(bi - bf2f(pih));
        u16* rowr = BT + (size_t)n * K4;
        rowr[0 * Kc + k] = brh; rowr[1 * Kc + k] = brl;
        rowr[2 * Kc + k] = nih; rowr[3 * Kc + k] = nil;
        u16* rowi = BT + (size_t)(Nh + n) * K4;
        rowi[0 * Kc + k] = pih; rowi[1 * Kc + k] = pil;
        rowi[2 * Kc + k] = brh; rowi[3 * Kc + k] = brl;
    }
}

// ---------------------------------------------------------------------------
// Deep-pipelined split-bf16 GEMM, m201-style phase schedule.
// 256x256 tile, BK=32, 8 waves (2M x 4N), ring of 4 LDS slots per operand.
// Per tile: {stage t+2; MFMA ph1; pre-read ph2 frags; vmcnt(4); barrier;
//            MFMA ph2; pre-read next tile's ph1 frags}.
// One barrier per tile; ds_reads overlap barrier wait; loads never drained
// to 0 in steady state.  Swizzle: chunk ^= (row>>1)&3 (0 conflicts, R3).
// ---------------------------------------------------------------------------
extern __shared__ char smem8p[];

#define MFMA16(ACC0, ACC1, ACC2, ACC3, A0, A1, A2, A3)                          \
    ACC0[0] = __builtin_amdgcn_mfma_f32_16x16x32_bf16(A0, b0, ACC0[0], 0, 0, 0); \
    ACC0[1] = __builtin_amdgcn_mfma_f32_16x16x32_bf16(A0, b1, ACC0[1], 0, 0, 0); \
    ACC0[2] = __builtin_amdgcn_mfma_f32_16x16x32_bf16(A0, b2, ACC0[2], 0, 0, 0); \
    ACC0[3] = __builtin_amdgcn_mfma_f32_16x16x32_bf16(A0, b3, ACC0[3], 0, 0, 0); \
    ACC1[0] = __builtin_amdgcn_mfma_f32_16x16x32_bf16(A1, b0, ACC1[0], 0, 0, 0); \
    ACC1[1] = __builtin_amdgcn_mfma_f32_16x16x32_bf16(A1, b1, ACC1[1], 0, 0, 0); \
    ACC1[2] = __builtin_amdgcn_mfma_f32_16x16x32_bf16(A1, b2, ACC1[2], 0, 0, 0); \
    ACC1[3] = __builtin_amdgcn_mfma_f32_16x16x32_bf16(A1, b3, ACC1[3], 0, 0, 0); \
    ACC2[0] = __builtin_amdgcn_mfma_f32_16x16x32_bf16(A2, b0, ACC2[0], 0, 0, 0); \
    ACC2[1] = __builtin_amdgcn_mfma_f32_16x16x32_bf16(A2, b1, ACC2[1], 0, 0, 0); \
    ACC2[2] = __builtin_amdgcn_mfma_f32_16x16x32_bf16(A2, b2, ACC2[2], 0, 0, 0); \
    ACC2[3] = __builtin_amdgcn_mfma_f32_16x16x32_bf16(A2, b3, ACC2[3], 0, 0, 0); \
    ACC3[0] = __builtin_amdgcn_mfma_f32_16x16x32_bf16(A3, b0, ACC3[0], 0, 0, 0); \
    ACC3[1] = __builtin_amdgcn_mfma_f32_16x16x32_bf16(A3, b1, ACC3[1], 0, 0, 0); \
    ACC3[2] = __builtin_amdgcn_mfma_f32_16x16x32_bf16(A3, b2, ACC3[2], 0, 0, 0); \
    ACC3[3] = __builtin_amdgcn_mfma_f32_16x16x32_bf16(A3, b3, ACC3[3], 0, 0, 0);

template <int EPI, int SWZ>
__global__ __launch_bounds__(512, 2) void gemm8p(
    const u16* __restrict__ A, const u16* __restrict__ B,
    const float* __restrict__ biasL, const float* __restrict__ biasR,
    u16* __restrict__ OutU, float* __restrict__ P01, float* __restrict__ P23,
    int Kc, int KcLog, int NH, int nt)
{
    char* ldsA = smem8p;              // 4 slots x 16384 B  (A tile 256x32 bf16)
    char* ldsB = smem8p + 65536;      // 4 slots x 16384 B

    const int tid = threadIdx.x;
    const int w = tid >> 6, lane = tid & 63;
    const int wr = w >> 2, wc = w & 3;           // 2M x 4N waves
    const int fr = lane & 15, kb = lane >> 4;

    int bx, by, z;
    if (SWZ) {
        int b = blockIdx.x;
        int xcd = b & 7, idx = b >> 3;
        bx = 4 * xcd + (idx & 3);                // 32 N-blocks
        by = idx >> 2;                           // 8 M-blocks
        z = 0;
    } else {
        bx = blockIdx.x; by = blockIdx.y; z = blockIdx.z;
    }
    const int n0 = bx * 256, m0 = by * 256;
    const size_t K4 = 4 * (size_t)Kc;

    // staging: thread covers row srow(+128), swizzled source chunk
    const int srow = tid >> 2;
    const int lk8 = (((tid & 3) ^ ((tid >> 3) & 3))) * 8;   // element offset
    const int wb = (tid >> 6) * 1024;                       // wave dest base (B)

    // frag read lane offset (bytes): row fr, chunk kb ^ ((fr>>1)&3)
    const int laneOff = fr * 64 + ((kb ^ ((fr >> 1) & 3)) << 4);

    f32x4 acc[8][4];
#pragma unroll
    for (int i = 0; i < 8; i++)
#pragma unroll
        for (int j = 0; j < 4; j++)
            acc[i][j] = (f32x4){0.f, 0.f, 0.f, 0.f};

    const int t0 = z * nt, te = t0 + nt;

    auto colA = [&](int t) {
        int k0 = t << 5;
        int seg = k0 >> KcLog, kk = k0 & (Kc - 1);
        int r3 = seg >= 3 ? seg - 3 : seg;
        int bs = seg >= 3 ? 2 : 0;
        return (bs + (r3 == 1 ? 1 : 0)) * Kc + kk;
    };
    auto colB = [&](int t) {
        int k0 = t << 5;
        int seg = k0 >> KcLog, kk = k0 & (Kc - 1);
        int r3 = seg >= 3 ? seg - 3 : seg;
        int bs = seg >= 3 ? 2 : 0;
        return (bs + (r3 == 2 ? 1 : 0)) * Kc + kk;
    };
    auto stageA = [&](int t) {
        const u16* src = A + (size_t)(m0 + srow) * K4 + colA(t) + lk8;
        char* dst = ldsA + (t & 3) * 16384 + wb;
        gload_lds16(src, dst);
        gload_lds16(src + (size_t)128 * K4, dst + 8192);
    };
    auto stageB = [&](int t) {
        const u16* src = B + (size_t)(n0 + srow) * K4 + colB(t) + lk8;
        char* dst = ldsB + (t & 3) * 16384 + wb;
        gload_lds16(src, dst);
        gload_lds16(src + (size_t)128 * K4, dst + 8192);
    };
    auto aBase = [&](int t) -> const char* {
        return ldsA + (t & 3) * 16384 + wr * 8192 + laneOff;
    };
    auto bBase = [&](int t) -> const char* {
        return ldsB + (t & 3) * 16384 + wc * 4096 + laneOff;
    };

    // prologue: stage tiles t0, t0+1; publish t0; pre-read its phase-1 frags
    stageA(t0); stageB(t0);
    if (t0 + 1 < te) { stageA(t0 + 1); stageB(t0 + 1); }
    if (t0 + 1 < te) asm volatile("s_waitcnt vmcnt(4)" ::: "memory");
    else             asm volatile("s_waitcnt vmcnt(0)" ::: "memory");
    asm volatile("s_barrier" ::: "memory");

    bf16x8 b0, b1, b2, b3, a0, a1, a2, a3;
    {
        const char* aS = aBase(t0);
        const char* bS = bBase(t0);
        b0 = *(const bf16x8*)(bS + 0 * 1024);
        b1 = *(const bf16x8*)(bS + 1 * 1024);
        b2 = *(const bf16x8*)(bS + 2 * 1024);
        b3 = *(const bf16x8*)(bS + 3 * 1024);
        a0 = *(const bf16x8*)(aS + 0 * 1024);
        a1 = *(const bf16x8*)(aS + 1 * 1024);
        a2 = *(const bf16x8*)(aS + 2 * 1024);
        a3 = *(const bf16x8*)(aS + 3 * 1024);
    }

    for (int t = t0; t < te; ++t) {
        // issue next-next tile's stages first (loads span the whole tile)
        if (t + 2 < te) { stageA(t + 2); stageB(t + 2); }

        // ---- phase 1: M-half 0 ----
        __builtin_amdgcn_s_setprio(1);
        MFMA16(acc[0], acc[1], acc[2], acc[3], a0, a1, a2, a3)
        __builtin_amdgcn_s_setprio(0);

        // pre-read phase-2 frags (slot t already published)
        const char* aS = aBase(t);
        bf16x8 c0 = *(const bf16x8*)(aS + 4096 + 0 * 1024);
        bf16x8 c1 = *(const bf16x8*)(aS + 4096 + 1 * 1024);
        bf16x8 c2 = *(const bf16x8*)(aS + 4096 + 2 * 1024);
        bf16x8 c3 = *(const bf16x8*)(aS + 4096 + 3 * 1024);

        // confirm tile t+1's 4 loads (issued during t-1); keep t+2's in flight
        if (t + 2 < te) asm volatile("s_waitcnt vmcnt(4)" ::: "memory");
        else            asm volatile("s_waitcnt vmcnt(0)" ::: "memory");
        asm volatile("s_barrier" ::: "memory");

        // ---- phase 2: M-half 1 ----
        __builtin_amdgcn_s_setprio(1);
        MFMA16(acc[4], acc[5], acc[6], acc[7], c0, c1, c2, c3)
        __builtin_amdgcn_s_setprio(0);

        // pre-read next tile's phase-1 frags (published by the barrier above)
        if (t + 1 < te) {
            const char* aN = aBase(t + 1);
            const char* bN = bBase(t + 1);
            b0 = *(const bf16x8*)(bN + 0 * 1024);
            b1 = *(const bf16x8*)(bN + 1 * 1024);
            b2 = *(const bf16x8*)(bN + 2 * 1024);
            b3 = *(const bf16x8*)(bN + 3 * 1024);
            a0 = *(const bf16x8*)(aN + 0 * 1024);
            a1 = *(const bf16x8*)(aN + 1 * 1024);
            a2 = *(const bf16x8*)(aN + 2 * 1024);
            a3 = *(const bf16x8*)(aN + 3 * 1024);
        }
    }

    // ---- epilogue ----
    const int fq = kb;
#pragma unroll
    for (int nj = 0; nj < 4; nj++) {
        int n = n0 + wc * 64 + nj * 16 + fr;
        if (EPI == 0) {
            bool left = (n < NH);
            int nn = left ? n : (n - NH);
            float bias = left ? biasL[n] : biasR[nn];
#pragma unroll
            for (int mi = 0; mi < 8; mi++) {
                int mb = m0 + wr * 128 + mi * 16 + fq * 4;
#pragma unroll
                for (int r = 0; r < 4; r++) {
                    float val = fmaxf(acc[mi][nj][r] + bias, 0.f);
                    u16 h = f2bf(val);
                    u16 lo = f2bf(val - bf2f(h));
                    size_t rb = (size_t)(mb + r) * (4 * (size_t)NH);
                    if (left) { OutU[rb + nn] = h; OutU[rb + NH + nn] = lo; }
                    else { OutU[rb + 2 * (size_t)NH + nn] = h; OutU[rb + 3 * (size_t)NH + nn] = lo; }
                }
            }
        } else {
            const size_t PSZ = (size_t)2048 * 2048;
            float* Out = (z < 2) ? (P01 + (size_t)z * PSZ) : (P23 + (size_t)(z - 2) * PSZ);
#pragma unroll
            for (int mi = 0; mi < 8; mi++) {
                int mb = m0 + wr * 128 + mi * 16 + fq * 4;
#pragma unroll
                for (int r = 0; r < 4; r++)
                    Out[(size_t)(mb + r) * 2048 + n] = acc[mi][nj][r];
            }
        }
    }
}

// ---------------------------------------------------------------------------
// Router: sum split-K partials + bias -> amp -> logits -> top-3 -> gates
// ---------------------------------------------------------------------------
__global__ __launch_bounds__(128) void router_kernel(
    const float* __restrict__ P01, const float* __restrict__ P23, int ZK,
    const float* __restrict__ b2,
    const float* __restrict__ w_gate, const float* __restrict__ w_noise,
    const float* __restrict__ noise_z, float* __restrict__ gates)
{
    __shared__ float s_amp[1024];
    __shared__ float s_logit[P_DIM];
    __shared__ int   s_idx[3];
    __shared__ float s_val[3];

    int b = blockIdx.x;
    const size_t PSZ = (size_t)2048 * 2048;
    const size_t roff = (size_t)b * 2048;

    for (int i = threadIdx.x; i < 1024; i += 128) {
        float orr = b2[i];
        float oii = b2[1024 + i];
        for (int zz = 0; zz < ZK; zz++) {
            const float* Pz = ((zz < 2) ? (P01 + (size_t)zz * PSZ)
                                        : (P23 + (size_t)(zz - 2) * PSZ)) + roff;
            orr += Pz[i];
            oii += Pz[1024 + i];
        }
        s_amp[i] = sqrtf(orr * orr + oii * oii);
    }
    __syncthreads();

    int p = threadIdx.x;
    if (p < P_DIM) {
        float cg = 0.f, cn = 0.f;
        for (int k = 0; k < 1024; k++) {
            float a = s_amp[k];
            cg = fmaf(a, w_gate[k * P_DIM + p], cg);
            cn = fmaf(a, w_noise[k * P_DIM + p], cn);
        }
        float ns = (cn > 20.f) ? cn : log1pf(expf(cn));
        ns += 0.01f;
        s_logit[p] = cg + noise_z[(size_t)b * P_DIM + p] * ns;
    }
    __syncthreads();

    if (threadIdx.x == 0) {
        int i0 = -1, i1 = -1, i2 = -1;
        float v0 = -1e30f, v1 = -1e30f, v2 = -1e30f;
        for (int i = 0; i < P_DIM; i++) {
            float t = s_logit[i];
            if (t > v0) { v0 = t; i0 = i; }
        }
        for (int i = 0; i < P_DIM; i++) {
            if (i == i0) continue;
            float t = s_logit[i];
            if (t > v1) { v1 = t; i1 = i; }
        }
        for (int i = 0; i < P_DIM; i++) {
            if (i == i0 || i == i1) continue;
            float t = s_logit[i];
            if (t > v2) { v2 = t; i2 = i; }
        }
        s_idx[0] = i0; s_idx[1] = i1; s_idx[2] = i2;
        s_val[0] = v0; s_val[1] = v1; s_val[2] = v2;
    }
    __syncthreads();

    if (p < P_DIM) {
        float m = s_val[0];
        float e0 = expf(s_val[0] - m);
        float e1 = expf(s_val[1] - m);
        float e2 = expf(s_val[2] - m);
        float inv = 1.f / (e0 + e1 + e2);
        float g = 0.f;
        if (p == s_idx[0]) g = e0 * inv;
        else if (p == s_idx[1]) g = e1 * inv;
        else if (p == s_idx[2]) g = e2 * inv;
        gates[(size_t)b * P_DIM + p] = g;
    }
}

// ---------------------------------------------------------------------------
extern "C" void kernel_launch(void* const* d_in, const int* in_sizes, int n_in,
                              void* d_out, int out_size, void* d_ws, size_t ws_size,
                              hipStream_t stream)
{
    const float* x       = (const float*)d_in[0];
    const float* w_start = (const float*)d_in[1];
    const float* b_start = (const float*)d_in[2];
    const float* w1      = (const float*)d_in[3];
    const float* b1      = (const float*)d_in[4];
    const float* w2      = (const float*)d_in[5];
    const float* b2      = (const float*)d_in[6];
    const float* w_gate  = (const float*)d_in[7];
    const float* w_noise = (const float*)d_in[8];
    const float* noise_z = (const float*)d_in[9];
    float* gates = (float*)d_out;

    const size_t MB = 1024 * 1024;
    char* base = (char*)d_ws;
    u16*  A1   = (u16*)(base + 16 * MB);     // [16,32) — dead after gemm1
    u16*  BT   = (u16*)(base + 32 * MB);     // [32,96) — BT1 then BT2
    u16*  A2   = (u16*)(base + 96 * MB);     // [96,160)
    float* P01 = (float*)base;               // partials z0,z1 -> [0,32)
    float* P23 = (float*)(base + 160 * MB);  // partials z2,z3 -> [160,192)

    int ZK = (ws_size >= (size_t)192 * MB) ? 4 : 2;

    hipFuncSetAttribute(reinterpret_cast<const void*>(&gemm8p<0, 1>),
                        hipFuncAttributeMaxDynamicSharedMemorySize, 131072);
    hipFuncSetAttribute(reinterpret_cast<const void*>(&gemm8p<1, 0>),
                        hipFuncAttributeMaxDynamicSharedMemorySize, 131072);

    fft_kernel<<<B_DIM, 256, 0, stream>>>(x, w_start, b_start, A1);

    // layer 1: M=2048, N=8192, Kc=1024 (K_eff=6144, nt=192); XCD-swizzled grid
    conv_bt_kernel<<<dim3(F_DIM / 32, H_DIM / 32), dim3(32, 8), 0, stream>>>(
        w1, BT, F_DIM, H_DIM);
    gemm8p<0, 1><<<256, 512, 131072, stream>>>(
        A1, BT, b1, b1 + H_DIM, A2, nullptr, nullptr, F_DIM, 10, H_DIM, 192);

    // layer 2: M=2048, N=2048, Kc=4096 (K_eff=24576, nt_total=768), split-K ZK
    conv_bt_kernel<<<dim3(H_DIM / 32, F_DIM / 32), dim3(32, 8), 0, stream>>>(
        w2, BT, H_DIM, F_DIM);
    gemm8p<1, 0><<<dim3(8, 8, ZK), 512, 131072, stream>>>(
        A2, BT, nullptr, nullptr, nullptr, P01, P23, H_DIM, 12, F_DIM, 768 / ZK);

    router_kernel<<<B_DIM, 128, 0, stream>>>(
        P01, P23, ZK, b2, w_gate, w_noise, noise_z, gates);
}